// Round 18
// baseline (48.936 us; speedup 1.0000x reference)
//
#include <hip/hip_runtime.h>
#include <hip/hip_bf16.h>
#include <math.h>

#define D_DIM   1024
#define NM      16
#define B_DIM   8
#define L_DIM   4096
#define SCALE_F 0.25f      // sqrt(1/N)
#define NK      5          // MFMA K-steps of 32 -> 160 taps total
#define NITER   8          // all 8 batch rows per block (block = d, grid 1024)
#define WBUF    1536       // wave-private window bytes: 768 bf16 (256 ctx + 512 body)

typedef __attribute__((ext_vector_type(8))) short bf16x8;   // 8 bf16 (4 VGPRs)
typedef __attribute__((ext_vector_type(4))) float f32x4;

union U4 { uint4 u; bf16x8 v; };

__device__ __forceinline__ unsigned short f2bf(float f) {
    __hip_bfloat16 h = __float2bfloat16(f);               // RNE
    return *reinterpret_cast<unsigned short*>(&h);
}
__device__ __forceinline__ float bflo(unsigned u) { return __uint_as_float(u << 16); }
__device__ __forceinline__ float bfhi(unsigned u) { return __uint_as_float(u & 0xffff0000u); }
// 16B-slot XOR swizzle (write/read identically); touches bits 4-6 only ->
// stays inside each 128B block, so in-bounds for the 1536B window.
__device__ __forceinline__ int swz(int a) { return a ^ (((a >> 7) & 7) << 4); }

// A-fragment for K-step k of dimension d (tap layout unchanged since R8):
// A[i,t'] = kernel_d[i + t'], lane=(i | g<<4), t' = 32k + 8g + e - 15.
__device__ void compute_af_k(int d, int lane, int k,
                             const float* __restrict__ p_logit,
                             const float* __restrict__ lqr,
                             const float* __restrict__ lqi,
                             const float* __restrict__ gr,
                             const float* __restrict__ gi,
                             char* __restrict__ afb)
{
    const int i = lane & 15, g = lane >> 4;
    const int t0 = i - 15 + 32 * k + 8 * g;
    const float t0f = (float)t0;

    float acc[8];
#pragma unroll
    for (int e = 0; e < 8; ++e) acc[e] = 0.0f;

#pragma unroll 1
    for (int n = 0; n < NM; ++n) {
        const int idx = d * NM + n;
        const float pp = 1.0f / (1.0f + __expf(-p_logit[idx]));
        const float CR = gr[idx] * (SCALE_F * pp);
        const float CI = gi[idx] * (SCALE_F * pp);
        const float LR = lqr[idx], LI = lqi[idx];

        float sq, cq; __sincosf(LI, &sq, &cq);
        const float eq = __expf(LR);
        const float qr = eq * cq, qi = eq * sq;          // q
        float s0, c0; __sincosf(t0f * LI, &s0, &c0);
        const float e0 = __expf(t0f * LR);
        float wr = e0 * c0, wi = e0 * s0;                // q^t0

#pragma unroll
        for (int e = 0; e < 8; ++e) {
            acc[e] = fmaf(CR, wr, fmaf(-CI, wi, acc[e]));
            const float nwr = fmaf(wr, qr, -wi * qi);
            const float nwi = fmaf(wr, qi,  wi * qr);
            wr = nwr; wi = nwi;
        }
    }

    unsigned pk[4];
#pragma unroll
    for (int e = 0; e < 8; ++e) {
        const unsigned b = (t0 + e >= 0) ? (unsigned)f2bf(acc[e]) : 0u;
        if ((e & 1) == 0) pk[e >> 1] = b; else pk[e >> 1] |= b << 16;
    }
    *reinterpret_cast<uint4*>(afb + k * 1024 + lane * 16) =
        make_uint4(pk[0], pk[1], pk[2], pk[3]);
}

// v13: BARRIER-FREE main loop. Persistent block = d (grid 1024, 4/CU); its
// 8 waves each own an eighth-row (512 outputs) with a WAVE-PRIVATE 768-elem
// reversed window (1536B, double-buffered, 3KB/wave): R14-R17's cooperative
// staging forced a __syncthreads per iteration, convoying all 8 waves to the
// slowest stager every ~750ns (occ ~49%, all pipes idle). Now the only
// barrier is after the cooperative af build; all LDS dependencies are
// same-wave (lgkmcnt). Wave-local reversed offsets re-derived from R14's
// proven mapping (byte = 2*((w0+511)-l)): rboff = 992-512tt-32j+64k+16g,
// roff = 1016-512tt-32j-8g, pack bases 1008-16*lane (body) / 1528-8*lane
// (context). Element orientation byte-identical => absmax 0.0625 invariant.
__global__ __launch_bounds__(512)
void ema_fused(const float* __restrict__ x,
               const float* __restrict__ p_logit,
               const float* __restrict__ lqr, const float* __restrict__ lqi,
               const float* __restrict__ gr, const float* __restrict__ gi,
               const float* __restrict__ omega,
               float* __restrict__ out)
{
    __shared__ __align__(16) char swin[8][2][WBUF];   // 24 KB wave-private
    __shared__ __align__(16) char safb[NK * 1024];    // 5 KB af table

    const int tid  = threadIdx.x;
    const int w    = tid >> 6;                  // wave = eighth of the row
    const int lane = tid & 63;
    const int d    = blockIdx.x;
    const int j    = lane & 15, g = lane >> 4;

    const size_t rstride = (size_t)D_DIM * L_DIM;
    const float* xw = x   + (size_t)d * L_DIM + w * 512;   // this wave's body
    float*       yw = out + (size_t)d * L_DIM + w * 512;
    const float  om = omega[d];

    // ---- issue row 0 loads: context (w>0) + body, all in flight ----
    float4 c4 = make_float4(0.f, 0.f, 0.f, 0.f);
    if (w != 0)
        c4 = *reinterpret_cast<const float4*>(xw - 256 + lane * 4);
    float4 r[2];
#pragma unroll
    for (int v = 0; v < 2; ++v)
        r[v] = *reinterpret_cast<const float4*>(xw + lane * 8 + 4 * v);

    // ---- cooperative af: waves 0..4 compute K-steps 0..4 ----
    if (w < NK)
        compute_af_k(d, lane, w, p_logit, lqr, lqi, gr, gi, safb);

    __syncthreads();                            // the ONLY block barrier

    bf16x8 af[NK];
#pragma unroll
    for (int k = 0; k < NK; ++k) {
        U4 u; u.u = *reinterpret_cast<const uint4*>(safb + k * 1024 + lane * 16);
        af[k] = u.v;
    }

    // Reversed wave-local pack. Body: lane covers x[w0+8lane..+7] -> uint4 at
    // 1008-16lane (elem e at byte +14-2e). Context: x[w0-256+4lane..+3] ->
    // uint2 at 1528-8lane (elem c at byte +6-2c); w=0 writes zeros.
#define PACK(dst)                                                              \
    {                                                                          \
        uint2 cpk = make_uint2(0u, 0u);                                        \
        if (w != 0) {                                                          \
            cpk.x = (unsigned)f2bf(c4.w) | ((unsigned)f2bf(c4.z) << 16);       \
            cpk.y = (unsigned)f2bf(c4.y) | ((unsigned)f2bf(c4.x) << 16);       \
        }                                                                      \
        *reinterpret_cast<uint2*>((dst) + swz(1528 - lane * 8)) = cpk;         \
        unsigned pk0 = (unsigned)f2bf(r[1].w) | ((unsigned)f2bf(r[1].z) << 16);\
        unsigned pk1 = (unsigned)f2bf(r[1].y) | ((unsigned)f2bf(r[1].x) << 16);\
        unsigned pk2 = (unsigned)f2bf(r[0].w) | ((unsigned)f2bf(r[0].z) << 16);\
        unsigned pk3 = (unsigned)f2bf(r[0].y) | ((unsigned)f2bf(r[0].x) << 16);\
        *reinterpret_cast<uint4*>((dst) + swz(1008 - lane * 16)) =             \
            make_uint4(pk0, pk1, pk2, pk3);                                    \
    }

    // ---- pack row 0 -> buf0; issue row 1 loads ----
    PACK(&swin[w][0][0]);
    if (w != 0)
        c4 = *reinterpret_cast<const float4*>(xw + rstride - 256 + lane * 4);
#pragma unroll
    for (int v = 0; v < 2; ++v)
        r[v] = *reinterpret_cast<const float4*>(xw + rstride + lane * 8 + 4 * v);

#pragma unroll 1
    for (int i = 0; i < NITER; ++i) {
        // ---- pack row i+1 into the other private buffer; issue row i+2 ----
        if (i < NITER - 1) {
            PACK(&swin[w][(i + 1) & 1][0]);
            if (i < NITER - 2) {
                const float* xn = xw + (size_t)(i + 2) * rstride;
                if (w != 0)
                    c4 = *reinterpret_cast<const float4*>(xn - 256 + lane * 4);
#pragma unroll
                for (int v = 0; v < 2; ++v)
                    r[v] = *reinterpret_cast<const float4*>(xn + lane * 8 + 4 * v);
            }
        }

        // ---- compute row i from the private window (same-wave lgkm order) ----
        const char* sb = &swin[w][i & 1][0];
        float* yb = yw + (size_t)i * rstride;
#pragma unroll
        for (int tt = 0; tt < 2; ++tt) {
            f32x4 acc = {0.0f, 0.0f, 0.0f, 0.0f};
#pragma unroll
            for (int k = 0; k < NK; ++k) {
                const int rboff = 992 - 512 * tt - 32 * j + 64 * k + 16 * g;  // [0,1296]
                U4 z; z.u = *reinterpret_cast<const uint4*>(sb + swz(rboff));
                acc = __builtin_amdgcn_mfma_f32_16x16x32_bf16(af[k], z.v, acc, 0, 0, 0);
            }
            const int roff = 1016 - 512 * tt - 32 * j - 8 * g;                // [0,1016]
            const uint2 z2 = *reinterpret_cast<const uint2*>(sb + swz(roff));
            acc.x = fmaf(om, bfhi(z2.y), acc.x);
            acc.y = fmaf(om, bflo(z2.y), acc.y);
            acc.z = fmaf(om, bfhi(z2.x), acc.z);
            acc.w = fmaf(om, bflo(z2.x), acc.w);
            __builtin_nontemporal_store(acc,
                reinterpret_cast<f32x4*>(yb + tt * 256 + 16 * j + 4 * g));
        }
    }
#undef PACK
}

extern "C" void kernel_launch(void* const* d_in, const int* in_sizes, int n_in,
                              void* d_out, int out_size, void* d_ws, size_t ws_size,
                              hipStream_t stream)
{
    const float* x   = (const float*)d_in[0];
    const float* pl  = (const float*)d_in[1];
    const float* lqr = (const float*)d_in[2];
    const float* lqi = (const float*)d_in[3];
    const float* gr  = (const float*)d_in[4];
    const float* gi  = (const float*)d_in[5];
    const float* om  = (const float*)d_in[6];
    float* out = (float*)d_out;

    dim3 grid(D_DIM), block(512);   // persistent: 1024 blocks = 4/CU resident
    ema_fused<<<grid, block, 0, stream>>>(x, pl, lqr, lqi, gr, gi, om, out);
}

// Round 19
// 48.730 us; speedup vs baseline: 1.0042x; 1.0042x over previous
//
#include <hip/hip_runtime.h>
#include <hip/hip_bf16.h>
#include <math.h>

#define D_DIM   1024
#define NM      16
#define B_DIM   8
#define L_DIM   4096
#define SCALE_F 0.25f      // sqrt(1/N)
#define NK      5          // MFMA K-steps of 32 -> 160 taps total
#define NITER   8          // all 8 batch rows per block (block = d, grid 1024)
#define WBUF    1536       // wave-private window bytes: 768 bf16 (256 ctx + 512 body)

typedef __attribute__((ext_vector_type(8))) short bf16x8;   // 8 bf16 (4 VGPRs)
typedef __attribute__((ext_vector_type(4))) float f32x4;

union U4 { uint4 u; bf16x8 v; };

__device__ __forceinline__ unsigned short f2bf(float f) {
    __hip_bfloat16 h = __float2bfloat16(f);               // RNE
    return *reinterpret_cast<unsigned short*>(&h);
}
__device__ __forceinline__ float bflo(unsigned u) { return __uint_as_float(u << 16); }
__device__ __forceinline__ float bfhi(unsigned u) { return __uint_as_float(u & 0xffff0000u); }
// 16B-slot XOR swizzle (write/read identically); touches bits 4-6 only.
__device__ __forceinline__ int swz(int a) { return a ^ (((a >> 7) & 7) << 4); }

// A-fragment for K-step k of dimension d (tap layout unchanged since R8):
// A[i,t'] = kernel_d[i + t'], lane=(i | g<<4), t' = 32k + 8g + e - 15.
__device__ void compute_af_k(int d, int lane, int k,
                             const float* __restrict__ p_logit,
                             const float* __restrict__ lqr,
                             const float* __restrict__ lqi,
                             const float* __restrict__ gr,
                             const float* __restrict__ gi,
                             char* __restrict__ afb)
{
    const int i = lane & 15, g = lane >> 4;
    const int t0 = i - 15 + 32 * k + 8 * g;
    const float t0f = (float)t0;

    float acc[8];
#pragma unroll
    for (int e = 0; e < 8; ++e) acc[e] = 0.0f;

#pragma unroll 1
    for (int n = 0; n < NM; ++n) {
        const int idx = d * NM + n;
        const float pp = 1.0f / (1.0f + __expf(-p_logit[idx]));
        const float CR = gr[idx] * (SCALE_F * pp);
        const float CI = gi[idx] * (SCALE_F * pp);
        const float LR = lqr[idx], LI = lqi[idx];

        float sq, cq; __sincosf(LI, &sq, &cq);
        const float eq = __expf(LR);
        const float qr = eq * cq, qi = eq * sq;          // q
        float s0, c0; __sincosf(t0f * LI, &s0, &c0);
        const float e0 = __expf(t0f * LR);
        float wr = e0 * c0, wi = e0 * s0;                // q^t0

#pragma unroll
        for (int e = 0; e < 8; ++e) {
            acc[e] = fmaf(CR, wr, fmaf(-CI, wi, acc[e]));
            const float nwr = fmaf(wr, qr, -wi * qi);
            const float nwi = fmaf(wr, qi,  wi * qr);
            wr = nwr; wi = nwi;
        }
    }

    unsigned pk[4];
#pragma unroll
    for (int e = 0; e < 8; ++e) {
        const unsigned b = (t0 + e >= 0) ? (unsigned)f2bf(acc[e]) : 0u;
        if ((e & 1) == 0) pk[e >> 1] = b; else pk[e >> 1] |= b << 16;
    }
    *reinterpret_cast<uint4*>(afb + k * 1024 + lane * 16) =
        make_uint4(pk[0], pk[1], pk[2], pk[3]);
}

// v14: R18 (barrier-free wave-private windows, persistent block=d) with
// DEPTH-2 REGISTER PREFETCH. Two load sets by row parity: row r's loads are
// issued at iter r-3 and packed at iter r-1 -> two full compute phases of
// HBM-latency cover (R14-R18's single-phase cover left PACK stalling on
// vmcnt; per-CU bytes-in-flight sat at the Little's-law knee ~53KB).
// ~6KB/wave in flight, ~100KB/CU. +12 VGPR (set fits 8 waves/SIMD).
// Window layout, swizzle, af build, offsets byte-identical to R18
// (absmax 0.0625 invariant).
__global__ __launch_bounds__(512)
void ema_fused(const float* __restrict__ x,
               const float* __restrict__ p_logit,
               const float* __restrict__ lqr, const float* __restrict__ lqi,
               const float* __restrict__ gr, const float* __restrict__ gi,
               const float* __restrict__ omega,
               float* __restrict__ out)
{
    __shared__ __align__(16) char swin[8][2][WBUF];   // 24 KB wave-private
    __shared__ __align__(16) char safb[NK * 1024];    // 5 KB af table

    const int tid  = threadIdx.x;
    const int w    = tid >> 6;                  // wave = eighth of the row
    const int lane = tid & 63;
    const int d    = blockIdx.x;
    const int j    = lane & 15, g = lane >> 4;

    const size_t rstride = (size_t)D_DIM * L_DIM;
    const float* xw = x   + (size_t)d * L_DIM + w * 512;   // this wave's body
    float*       yw = out + (size_t)d * L_DIM + w * 512;
    const float  om = omega[d];

    // Two prefetch register sets, indexed by row parity.
    float4 c4s[2];
    float4 rs[2][2];
    c4s[0] = make_float4(0.f, 0.f, 0.f, 0.f);
    c4s[1] = make_float4(0.f, 0.f, 0.f, 0.f);

#define LOAD(set, row)                                                         \
    {                                                                          \
        const float* xn = xw + (size_t)(row) * rstride;                        \
        if (w != 0)                                                            \
            c4s[set] = *reinterpret_cast<const float4*>(xn - 256 + lane * 4);  \
        rs[set][0] = *reinterpret_cast<const float4*>(xn + lane * 8);          \
        rs[set][1] = *reinterpret_cast<const float4*>(xn + lane * 8 + 4);      \
    }

    // ---- issue rows 0 and 1 (both sets in flight through the af build) ----
    LOAD(0, 0);
    LOAD(1, 1);

    // ---- cooperative af: waves 0..4 compute K-steps 0..4 ----
    if (w < NK)
        compute_af_k(d, lane, w, p_logit, lqr, lqi, gr, gi, safb);

    __syncthreads();                            // the ONLY block barrier

    bf16x8 af[NK];
#pragma unroll
    for (int k = 0; k < NK; ++k) {
        U4 u; u.u = *reinterpret_cast<const uint4*>(safb + k * 1024 + lane * 16);
        af[k] = u.v;
    }

    // Reversed wave-local pack from set s. Body: lane covers x[w0+8lane..+7]
    // -> uint4 at 1008-16lane. Context: x[w0-256+4lane..+3] -> uint2 at
    // 1528-8lane; w=0 writes zeros.
#define PACK(dst, s)                                                           \
    {                                                                          \
        uint2 cpk = make_uint2(0u, 0u);                                        \
        if (w != 0) {                                                          \
            cpk.x = (unsigned)f2bf(c4s[s].w) | ((unsigned)f2bf(c4s[s].z) << 16);\
            cpk.y = (unsigned)f2bf(c4s[s].y) | ((unsigned)f2bf(c4s[s].x) << 16);\
        }                                                                      \
        *reinterpret_cast<uint2*>((dst) + swz(1528 - lane * 8)) = cpk;         \
        unsigned pk0 = (unsigned)f2bf(rs[s][1].w) | ((unsigned)f2bf(rs[s][1].z) << 16);\
        unsigned pk1 = (unsigned)f2bf(rs[s][1].y) | ((unsigned)f2bf(rs[s][1].x) << 16);\
        unsigned pk2 = (unsigned)f2bf(rs[s][0].w) | ((unsigned)f2bf(rs[s][0].z) << 16);\
        unsigned pk3 = (unsigned)f2bf(rs[s][0].y) | ((unsigned)f2bf(rs[s][0].x) << 16);\
        *reinterpret_cast<uint4*>((dst) + swz(1008 - lane * 16)) =             \
            make_uint4(pk0, pk1, pk2, pk3);                                    \
    }

    // ---- pack row 0 -> buf0; refill set0 with row 2 ----
    PACK(&swin[w][0][0], 0);
    LOAD(0, 2);

#pragma unroll 1
    for (int i = 0; i < NITER; ++i) {
        // ---- pack row i+1 (loads issued at iter i-2: 2 phases of cover);
        //      refill the freed set with row i+3 ----
        if (i < NITER - 1) {
            if ((i & 1) == 0) { PACK(&swin[w][(i + 1) & 1][0], 1); }
            else              { PACK(&swin[w][(i + 1) & 1][0], 0); }
            if (i + 3 < NITER) {
                if (((i + 3) & 1) == 0) { LOAD(0, i + 3); }
                else                    { LOAD(1, i + 3); }
            }
        }

        // ---- compute row i from the private window (same-wave lgkm order) ----
        const char* sb = &swin[w][i & 1][0];
        float* yb = yw + (size_t)i * rstride;
#pragma unroll
        for (int tt = 0; tt < 2; ++tt) {
            f32x4 acc = {0.0f, 0.0f, 0.0f, 0.0f};
#pragma unroll
            for (int k = 0; k < NK; ++k) {
                const int rboff = 992 - 512 * tt - 32 * j + 64 * k + 16 * g;  // [0,1296]
                U4 z; z.u = *reinterpret_cast<const uint4*>(sb + swz(rboff));
                acc = __builtin_amdgcn_mfma_f32_16x16x32_bf16(af[k], z.v, acc, 0, 0, 0);
            }
            const int roff = 1016 - 512 * tt - 32 * j - 8 * g;                // [0,1016]
            const uint2 z2 = *reinterpret_cast<const uint2*>(sb + swz(roff));
            acc.x = fmaf(om, bfhi(z2.y), acc.x);
            acc.y = fmaf(om, bflo(z2.y), acc.y);
            acc.z = fmaf(om, bfhi(z2.x), acc.z);
            acc.w = fmaf(om, bflo(z2.x), acc.w);
            __builtin_nontemporal_store(acc,
                reinterpret_cast<f32x4*>(yb + tt * 256 + 16 * j + 4 * g));
        }
    }
#undef PACK
#undef LOAD
}

extern "C" void kernel_launch(void* const* d_in, const int* in_sizes, int n_in,
                              void* d_out, int out_size, void* d_ws, size_t ws_size,
                              hipStream_t stream)
{
    const float* x   = (const float*)d_in[0];
    const float* pl  = (const float*)d_in[1];
    const float* lqr = (const float*)d_in[2];
    const float* lqi = (const float*)d_in[3];
    const float* gr  = (const float*)d_in[4];
    const float* gi  = (const float*)d_in[5];
    const float* om  = (const float*)d_in[6];
    float* out = (float*)d_out;

    dim3 grid(D_DIM), block(512);   // persistent: 1024 blocks = 4/CU resident
    ema_fused<<<grid, block, 0, stream>>>(x, pl, lqr, lqi, gr, gi, om, out);
}